// Round 3
// baseline (73.070 us; speedup 1.0000x reference)
//
#include <hip/hip_runtime.h>
#include <math.h>

#define QPB 64           // queries per block (one per lane)
#define CHUNKS 4         // j-chunks (waves) per block
#define MAIN_BLOCK (QPB * CHUNKS)   // 256 threads
#define JPART 8          // j-partitions across blocks (occupancy lever)
#define BIGV 1e10f
#define EPSV 1e-8f

// kernel 1: sq[i] = x*x + y*y  (matches np.sum(pc*pc, axis=1) rounding)
__global__ void esdf_sq_kernel(const float2* __restrict__ pc,
                               float* __restrict__ sq, int n) {
#pragma clang fp contract(off)
    int i = blockIdx.x * blockDim.x + threadIdx.x;
    if (i < n) {
        float2 p = pc[i];
        float xx = p.x * p.x;
        float yy = p.y * p.y;
        sq[i] = xx + yy;
    }
}

// kernel 2: partial per-row argmin of d2 = max(sq_i + sq_j - 2*dot(i,j), 0),
// j != i, over this block's j-partition. Writes (best, idx) partials.
__global__ __launch_bounds__(MAIN_BLOCK)
void esdf_nn_partial(const float2* __restrict__ pc,
                     const float* __restrict__ sq,
                     float* __restrict__ pbest,
                     int* __restrict__ pidx, int n) {
#pragma clang fp contract(off)
    const int lane  = threadIdx.x & 63;
    const int chunk = __builtin_amdgcn_readfirstlane((int)(threadIdx.x >> 6));
    const int qblk  = blockIdx.x >> 3;           // 256 query blocks
    const int jpart = blockIdx.x & (JPART - 1);
    const int qbase = qblk * QPB;
    const int i     = qbase + lane;

    const float2 pi  = pc[i];
    const float  sqi = sq[i];
    const float  xi  = pi.x, yi = pi.y;

    const int JC     = n / (JPART * CHUNKS);     // 512 j's per wave
    const int j0base = jpart * (n / JPART) + chunk * JC;

    // 4 independent argmin chains (ILP); k&3 interleave keeps j-classes disjoint
    float best0 = BIGV, best1 = BIGV, best2 = BIGV, best3 = BIGV;
    int   bi0 = 0, bi1 = 1, bi2 = 2, bi3 = 3;

    const float4* pc4 = (const float4*)pc;       // pc4[k] holds points 2k, 2k+1
    const float4* sq4 = (const float4*)sq;

    for (int jt = 0; jt < JC; jt += 8) {
        const int j0 = j0base + jt;              // wave-uniform
        float4 p01 = pc4[(j0 >> 1) + 0];
        float4 p23 = pc4[(j0 >> 1) + 1];
        float4 p45 = pc4[(j0 >> 1) + 2];
        float4 p67 = pc4[(j0 >> 1) + 3];
        float4 sA  = sq4[(j0 >> 2) + 0];
        float4 sB  = sq4[(j0 >> 2) + 1];
        float xs[8] = {p01.x, p01.z, p23.x, p23.z, p45.x, p45.z, p67.x, p67.z};
        float ys[8] = {p01.y, p01.w, p23.y, p23.w, p45.y, p45.w, p67.y, p67.w};
        float ss[8] = {sA.x, sA.y, sA.z, sA.w, sB.x, sB.y, sB.z, sB.w};

        // wave-uniform: does [j0, j0+8) intersect this block's query range?
        const bool safe = (j0 + 8 <= qbase) || (j0 >= qbase + QPB);
        if (safe) {
#pragma unroll
            for (int k = 0; k < 8; ++k) {
                float dot = fmaf(ys[k], yi, xs[k] * xi);   // BLAS fma order
                float s   = sqi + ss[k];
                float d2  = fmaf(-2.0f, dot, s);
                d2 = fmaxf(d2, 0.0f);
                switch (k & 3) {
                    case 0: if (d2 < best0) { best0 = d2; bi0 = j0 + k; } break;
                    case 1: if (d2 < best1) { best1 = d2; bi1 = j0 + k; } break;
                    case 2: if (d2 < best2) { best2 = d2; bi2 = j0 + k; } break;
                    default:if (d2 < best3) { best3 = d2; bi3 = j0 + k; } break;
                }
            }
        } else {
#pragma unroll
            for (int k = 0; k < 8; ++k) {
                float dot = fmaf(ys[k], yi, xs[k] * xi);
                float s   = sqi + ss[k];
                float d2  = fmaf(-2.0f, dot, s);
                d2 = fmaxf(d2, 0.0f);
                bool ok = (j0 + k) != i;         // exclude diagonal (ref adds BIG)
                switch (k & 3) {
                    case 0: if (ok && d2 < best0) { best0 = d2; bi0 = j0 + k; } break;
                    case 1: if (ok && d2 < best1) { best1 = d2; bi1 = j0 + k; } break;
                    case 2: if (ok && d2 < best2) { best2 = d2; bi2 = j0 + k; } break;
                    default:if (ok && d2 < best3) { best3 = d2; bi3 = j0 + k; } break;
                }
            }
        }
    }

    // merge 4 accumulators (tie -> smaller index = numpy argmin)
    float bA; int iA;
    if (best0 < best1 || (best0 == best1 && bi0 < bi1)) { bA = best0; iA = bi0; }
    else                                                 { bA = best1; iA = bi1; }
    float bB; int iB;
    if (best2 < best3 || (best2 == best3 && bi2 < bi3)) { bB = best2; iB = bi2; }
    else                                                 { bB = best3; iB = bi3; }
    float best; int bi;
    if (bA < bB || (bA == bB && iA < iB)) { best = bA; bi = iA; }
    else                                   { best = bB; bi = iB; }

    __shared__ float sbest[CHUNKS][QPB];
    __shared__ int   sbidx[CHUNKS][QPB];
    sbest[chunk][lane] = best;
    sbidx[chunk][lane] = bi;
    __syncthreads();

    if (threadIdx.x < QPB) {
        const int q = threadIdx.x;
        float b = sbest[0][q]; int ix = sbidx[0][q];
#pragma unroll
        for (int c = 1; c < CHUNKS; ++c) {
            float bb = sbest[c][q]; int jj = sbidx[c][q];
            if (bb < b || (bb == b && jj < ix)) { b = bb; ix = jj; }
        }
        pbest[jpart * n + qbase + q] = b;
        pidx [jpart * n + qbase + q] = ix;
    }
}

// kernel 3: reduce JPART partials per query + epilogue
__global__ void esdf_finalize(const float2* __restrict__ pc,
                              const float* __restrict__ pbest,
                              const int* __restrict__ pidx,
                              float* __restrict__ out, int n) {
#pragma clang fp contract(off)
    int q = blockIdx.x * blockDim.x + threadIdx.x;
    if (q >= n) return;
    float b = pbest[q]; int ix = pidx[q];
#pragma unroll
    for (int p = 1; p < JPART; ++p) {
        float bb = pbest[p * n + q];
        int   jj = pidx [p * n + q];
        if (bb < b || (bb == b && jj < ix)) { b = bb; ix = jj; }
    }
    float esdf = sqrtf(b);
    float2 pn = pc[ix];
    float2 pq = pc[q];
    float dx = pq.x - pn.x;
    float dy = pq.y - pn.y;
    float a  = dx * dx;
    float c2 = dy * dy;
    float nrm = sqrtf(a + c2);
    float inv = nrm + EPSV;
    float gx = dx / inv;
    float gy = dy / inv;
    // out = mu(4,N) then lam(3,N), flat
    out[0 * n + q] = gx;
    out[1 * n + q] = -gx;
    out[2 * n + q] = gy;
    out[3 * n + q] = -gy;
    out[4 * n + q] = gx;
    out[5 * n + q] = gy;
    out[6 * n + q] = esdf / 10.0f;
}

extern "C" void kernel_launch(void* const* d_in, const int* in_sizes, int n_in,
                              void* d_out, int out_size, void* d_ws, size_t ws_size,
                              hipStream_t stream) {
    const float2* pc = (const float2*)d_in[0];
    float* out = (float*)d_out;
    const int n = in_sizes[0] / 2;               // 16384

    // ws layout: sq[n] | pbest[JPART*n] | pidx[JPART*n]  (~1.1 MB)
    float* sq    = (float*)d_ws;
    float* pbest = sq + n;
    int*   pidx  = (int*)(pbest + JPART * n);

    esdf_sq_kernel<<<(n + 255) / 256, 256, 0, stream>>>(pc, sq, n);
    esdf_nn_partial<<<(n / QPB) * JPART, MAIN_BLOCK, 0, stream>>>(pc, sq, pbest, pidx, n);
    esdf_finalize<<<(n + 255) / 256, 256, 0, stream>>>(pc, pbest, pidx, out, n);
}

// Round 4
// 69.213 us; speedup vs baseline: 1.0557x; 1.0557x over previous
//
#include <hip/hip_runtime.h>
#include <math.h>

#define QPB 256          // queries per block (one per thread, 4 waves)
#define JWIN 512         // shared j-window per block (6 KB -> K$-resident)
#define JPART 32         // n / JWIN
#define BIGV 1e10f
#define EPSV 1e-8f

// kernel 1: sq[i] = x*x + y*y (reference rounding) + init packed keys
__global__ void esdf_prep(const float2* __restrict__ pc,
                          float* __restrict__ sq,
                          unsigned long long* __restrict__ key, int n) {
#pragma clang fp contract(off)
    int i = blockIdx.x * blockDim.x + threadIdx.x;
    if (i < n) {
        float2 p = pc[i];
        float xx = p.x * p.x;
        float yy = p.y * p.y;
        sq[i] = xx + yy;
        key[i] = ~0ull;
    }
}

// kernel 2: each thread owns one query; block sweeps one shared 512-j window.
// Partial argmin merged globally via atomicMin on key = (d2_bits<<32)|j.
__global__ __launch_bounds__(QPB)
void esdf_nn(const float2* __restrict__ pc,
             const float* __restrict__ sq,
             unsigned long long* __restrict__ key, int n) {
#pragma clang fp contract(off)
    const int tid   = threadIdx.x;
    const int qblk  = blockIdx.x >> 5;           // 64 query blocks
    const int jpart = blockIdx.x & (JPART - 1);  // 32 j-windows
    const int qbase = qblk * QPB;
    const int q     = qbase + tid;
    const int jbase = jpart * JWIN;

    const float2 pi  = pc[q];
    const float  sqi = sq[q];
    const float  xi  = pi.x, yi = pi.y;

    // 4 independent argmin chains (strict < keeps lowest j within each chain)
    float best0 = BIGV, best1 = BIGV, best2 = BIGV, best3 = BIGV;
    int   bi0 = 0, bi1 = 1, bi2 = 2, bi3 = 3;

    const float4* pc4 = (const float4*)pc;       // pc4[k] holds points 2k,2k+1
    const float4* sq4 = (const float4*)sq;

    for (int jt = 0; jt < JWIN; jt += 8) {
        const int j0 = jbase + jt;               // block-uniform -> s_load path
        float4 p01 = pc4[(j0 >> 1) + 0];
        float4 p23 = pc4[(j0 >> 1) + 1];
        float4 p45 = pc4[(j0 >> 1) + 2];
        float4 p67 = pc4[(j0 >> 1) + 3];
        float4 sA  = sq4[(j0 >> 2) + 0];
        float4 sB  = sq4[(j0 >> 2) + 1];
        float xs[8] = {p01.x, p01.z, p23.x, p23.z, p45.x, p45.z, p67.x, p67.z};
        float ys[8] = {p01.y, p01.w, p23.y, p23.w, p45.y, p45.w, p67.y, p67.w};
        float ss[8] = {sA.x, sA.y, sA.z, sA.w, sB.x, sB.y, sB.z, sB.w};

        // block-uniform: does [j0, j0+8) intersect [qbase, qbase+QPB)?
        const bool safe = (j0 + 8 <= qbase) || (j0 >= qbase + QPB);
        if (safe) {
#pragma unroll
            for (int k = 0; k < 8; ++k) {
                float dot = fmaf(ys[k], yi, xs[k] * xi);   // BLAS fma order
                float s   = sqi + ss[k];
                float d2  = fmaf(-2.0f, dot, s);
                d2 = fmaxf(d2, 0.0f);
                switch (k & 3) {
                    case 0: if (d2 < best0) { best0 = d2; bi0 = j0 + k; } break;
                    case 1: if (d2 < best1) { best1 = d2; bi1 = j0 + k; } break;
                    case 2: if (d2 < best2) { best2 = d2; bi2 = j0 + k; } break;
                    default:if (d2 < best3) { best3 = d2; bi3 = j0 + k; } break;
                }
            }
        } else {
#pragma unroll
            for (int k = 0; k < 8; ++k) {
                float dot = fmaf(ys[k], yi, xs[k] * xi);
                float s   = sqi + ss[k];
                float d2  = fmaf(-2.0f, dot, s);
                d2 = fmaxf(d2, 0.0f);
                bool ok = (j0 + k) != q;         // exclude diagonal (ref adds BIG)
                switch (k & 3) {
                    case 0: if (ok && d2 < best0) { best0 = d2; bi0 = j0 + k; } break;
                    case 1: if (ok && d2 < best1) { best1 = d2; bi1 = j0 + k; } break;
                    case 2: if (ok && d2 < best2) { best2 = d2; bi2 = j0 + k; } break;
                    default:if (ok && d2 < best3) { best3 = d2; bi3 = j0 + k; } break;
                }
            }
        }
    }

    // pack (d2,j) -> u64 key; lexicographic min == numpy argmin w/ low-j ties
    unsigned long long k0 = ((unsigned long long)__float_as_uint(best0) << 32) | (unsigned)bi0;
    unsigned long long k1 = ((unsigned long long)__float_as_uint(best1) << 32) | (unsigned)bi1;
    unsigned long long k2 = ((unsigned long long)__float_as_uint(best2) << 32) | (unsigned)bi2;
    unsigned long long k3 = ((unsigned long long)__float_as_uint(best3) << 32) | (unsigned)bi3;
    unsigned long long ka = k0 < k1 ? k0 : k1;
    unsigned long long kb = k2 < k3 ? k2 : k3;
    unsigned long long kk = ka < kb ? ka : kb;
    atomicMin(&key[q], kk);
}

// kernel 3: unpack key + epilogue
__global__ void esdf_finalize(const float2* __restrict__ pc,
                              const unsigned long long* __restrict__ key,
                              float* __restrict__ out, int n) {
#pragma clang fp contract(off)
    int q = blockIdx.x * blockDim.x + threadIdx.x;
    if (q >= n) return;
    unsigned long long k = key[q];
    int   ix = (int)(k & 0xffffffffull);
    float b  = __uint_as_float((unsigned)(k >> 32));
    float esdf = sqrtf(b);
    float2 pn = pc[ix];
    float2 pq = pc[q];
    float dx = pq.x - pn.x;
    float dy = pq.y - pn.y;
    float a  = dx * dx;
    float c2 = dy * dy;
    float nrm = sqrtf(a + c2);
    float inv = nrm + EPSV;
    float gx = dx / inv;
    float gy = dy / inv;
    // out = mu(4,N) then lam(3,N), flat
    out[0 * n + q] = gx;
    out[1 * n + q] = -gx;
    out[2 * n + q] = gy;
    out[3 * n + q] = -gy;
    out[4 * n + q] = gx;
    out[5 * n + q] = gy;
    out[6 * n + q] = esdf / 10.0f;
}

extern "C" void kernel_launch(void* const* d_in, const int* in_sizes, int n_in,
                              void* d_out, int out_size, void* d_ws, size_t ws_size,
                              hipStream_t stream) {
    const float2* pc = (const float2*)d_in[0];
    float* out = (float*)d_out;
    const int n = in_sizes[0] / 2;               // 16384

    // ws layout: sq[n] f32 (64KB) | key[n] u64 (128KB)
    float* sq = (float*)d_ws;
    unsigned long long* key = (unsigned long long*)(sq + n);

    esdf_prep<<<(n + 255) / 256, 256, 0, stream>>>(pc, sq, key, n);
    esdf_nn<<<(n / QPB) * JPART, QPB, 0, stream>>>(pc, sq, key, n);
    esdf_finalize<<<(n + 255) / 256, 256, 0, stream>>>(pc, key, out, n);
}

// Round 5
// 61.013 us; speedup vs baseline: 1.1976x; 1.1344x over previous
//
#include <hip/hip_runtime.h>
#include <math.h>

#define QPB 256          // queries per block (one per thread, 4 waves)
#define JWIN 512         // shared j-window per block, staged in LDS (6 KB)
#define JPART 32         // n / JWIN
#define BIGV 1e10f
#define EPSV 1e-8f

// kernel 1: sq[i] = x*x + y*y (reference rounding) + init packed keys
__global__ void esdf_prep(const float2* __restrict__ pc,
                          float* __restrict__ sq,
                          unsigned long long* __restrict__ key, int n) {
#pragma clang fp contract(off)
    int i = blockIdx.x * blockDim.x + threadIdx.x;
    if (i < n) {
        float2 p = pc[i];
        float xx = p.x * p.x;
        float yy = p.y * p.y;
        sq[i] = xx + yy;
        key[i] = ~0ull;
    }
}

// kernel 2: each thread owns one query; block stages one 512-j window in LDS
// (coalesced vector loads, NO scalar-cache traffic in the loop), then scans.
// Partial argmin merged globally via atomicMin on key = (d2_bits<<32)|j.
__global__ __launch_bounds__(QPB)
void esdf_nn(const float2* __restrict__ pc,
             const float* __restrict__ sq,
             unsigned long long* __restrict__ key, int n) {
#pragma clang fp contract(off)
    const int tid   = threadIdx.x;
    const int qblk  = blockIdx.x >> 5;           // 64 query blocks
    const int jpart = blockIdx.x & (JPART - 1);  // 32 j-windows
    const int qbase = qblk * QPB;
    const int q     = qbase + tid;
    const int jbase = jpart * JWIN;

    // --- stage j-window into LDS (vector path, coalesced) ---
    __shared__ float4 spc[JWIN / 2];   // 256 float4 = 512 float2 points
    __shared__ float4 ssq[JWIN / 4];   // 128 float4 = 512 sq values
    {
        const float4* pc4 = (const float4*)pc;
        const float4* sq4 = (const float4*)sq;
        spc[tid] = pc4[(jbase >> 1) + tid];
        if (tid < JWIN / 4) ssq[tid] = sq4[(jbase >> 2) + tid];
    }

    const float2 pi  = pc[q];
    const float  sqi = sq[q];
    const float  xi  = pi.x, yi = pi.y;
    __syncthreads();

    // 4 independent argmin chains (strict < keeps lowest j within each chain)
    float best0 = BIGV, best1 = BIGV, best2 = BIGV, best3 = BIGV;
    int   bi0 = 0, bi1 = 1, bi2 = 2, bi3 = 3;

    for (int jt = 0; jt < JWIN; jt += 8) {
        const int j0 = jbase + jt;               // block-uniform
        float4 p01 = spc[(jt >> 1) + 0];         // ds_read_b128 broadcasts
        float4 p23 = spc[(jt >> 1) + 1];
        float4 p45 = spc[(jt >> 1) + 2];
        float4 p67 = spc[(jt >> 1) + 3];
        float4 sA  = ssq[(jt >> 2) + 0];
        float4 sB  = ssq[(jt >> 2) + 1];
        float xs[8] = {p01.x, p01.z, p23.x, p23.z, p45.x, p45.z, p67.x, p67.z};
        float ys[8] = {p01.y, p01.w, p23.y, p23.w, p45.y, p45.w, p67.y, p67.w};
        float ss[8] = {sA.x, sA.y, sA.z, sA.w, sB.x, sB.y, sB.z, sB.w};

        // block-uniform: does [j0, j0+8) intersect [qbase, qbase+QPB)?
        const bool safe = (j0 + 8 <= qbase) || (j0 >= qbase + QPB);
        if (safe) {
#pragma unroll
            for (int k = 0; k < 8; ++k) {
                float dot = fmaf(ys[k], yi, xs[k] * xi);   // BLAS fma order
                float s   = sqi + ss[k];
                float d2  = fmaf(-2.0f, dot, s);
                d2 = fmaxf(d2, 0.0f);
                switch (k & 3) {
                    case 0: if (d2 < best0) { best0 = d2; bi0 = j0 + k; } break;
                    case 1: if (d2 < best1) { best1 = d2; bi1 = j0 + k; } break;
                    case 2: if (d2 < best2) { best2 = d2; bi2 = j0 + k; } break;
                    default:if (d2 < best3) { best3 = d2; bi3 = j0 + k; } break;
                }
            }
        } else {
#pragma unroll
            for (int k = 0; k < 8; ++k) {
                float dot = fmaf(ys[k], yi, xs[k] * xi);
                float s   = sqi + ss[k];
                float d2  = fmaf(-2.0f, dot, s);
                d2 = fmaxf(d2, 0.0f);
                bool ok = (j0 + k) != q;         // exclude diagonal (ref adds BIG)
                switch (k & 3) {
                    case 0: if (ok && d2 < best0) { best0 = d2; bi0 = j0 + k; } break;
                    case 1: if (ok && d2 < best1) { best1 = d2; bi1 = j0 + k; } break;
                    case 2: if (ok && d2 < best2) { best2 = d2; bi2 = j0 + k; } break;
                    default:if (ok && d2 < best3) { best3 = d2; bi3 = j0 + k; } break;
                }
            }
        }
    }

    // pack (d2,j) -> u64 key; lexicographic min == numpy argmin w/ low-j ties
    unsigned long long k0 = ((unsigned long long)__float_as_uint(best0) << 32) | (unsigned)bi0;
    unsigned long long k1 = ((unsigned long long)__float_as_uint(best1) << 32) | (unsigned)bi1;
    unsigned long long k2 = ((unsigned long long)__float_as_uint(best2) << 32) | (unsigned)bi2;
    unsigned long long k3 = ((unsigned long long)__float_as_uint(best3) << 32) | (unsigned)bi3;
    unsigned long long ka = k0 < k1 ? k0 : k1;
    unsigned long long kb = k2 < k3 ? k2 : k3;
    unsigned long long kk = ka < kb ? ka : kb;
    atomicMin(&key[q], kk);
}

// kernel 3: unpack key + epilogue
__global__ void esdf_finalize(const float2* __restrict__ pc,
                              const unsigned long long* __restrict__ key,
                              float* __restrict__ out, int n) {
#pragma clang fp contract(off)
    int q = blockIdx.x * blockDim.x + threadIdx.x;
    if (q >= n) return;
    unsigned long long k = key[q];
    int   ix = (int)(k & 0xffffffffull);
    float b  = __uint_as_float((unsigned)(k >> 32));
    float esdf = sqrtf(b);
    float2 pn = pc[ix];
    float2 pq = pc[q];
    float dx = pq.x - pn.x;
    float dy = pq.y - pn.y;
    float a  = dx * dx;
    float c2 = dy * dy;
    float nrm = sqrtf(a + c2);
    float inv = nrm + EPSV;
    float gx = dx / inv;
    float gy = dy / inv;
    // out = mu(4,N) then lam(3,N), flat
    out[0 * n + q] = gx;
    out[1 * n + q] = -gx;
    out[2 * n + q] = gy;
    out[3 * n + q] = -gy;
    out[4 * n + q] = gx;
    out[5 * n + q] = gy;
    out[6 * n + q] = esdf / 10.0f;
}

extern "C" void kernel_launch(void* const* d_in, const int* in_sizes, int n_in,
                              void* d_out, int out_size, void* d_ws, size_t ws_size,
                              hipStream_t stream) {
    const float2* pc = (const float2*)d_in[0];
    float* out = (float*)d_out;
    const int n = in_sizes[0] / 2;               // 16384

    // ws layout: sq[n] f32 (64KB) | key[n] u64 (128KB)
    float* sq = (float*)d_ws;
    unsigned long long* key = (unsigned long long*)(sq + n);

    esdf_prep<<<(n + 255) / 256, 256, 0, stream>>>(pc, sq, key, n);
    esdf_nn<<<(n / QPB) * JPART, QPB, 0, stream>>>(pc, sq, key, n);
    esdf_finalize<<<(n + 255) / 256, 256, 0, stream>>>(pc, key, out, n);
}